// Round 12
// baseline (43250.549 us; speedup 1.0000x reference)
//
#include <hip/hip_runtime.h>
#include <math.h>

// ---------------------------------------------------------------------------
// Fused 16-layer LSTM pipeline (H=512, T=4096) + MLP head.
// BARRIER-FREE, WAVE-AUTONOMOUS redesign (r12):
//  - 256 blocks = 16 layers x 16 blocks/layer, 1024 thr = 16 waves, 1/CU.
//  - Each WAVE is an independent engine for 2 h-indices (hi0 = b*32+2*wv):
//    lane cs (0..63) owns an 8-float k-slice of the x-half AND h-half.
//    Weights: 2 hi x 4 gates x (4+4) half2 = 64 u32/lane (f16, reg-resident).
//  - Ring words are u64 {tag32 | 2xf16 h}: a lane's h-slice = 4 words = 32B
//    = two dwordx4 sc1 loads, consumed DIRECTLY into dot2 operands.
//    -> NO LDS, NO BARRIERS anywhere in the step loop. The r4-r11 structure
//    paid BAR1+BAR2 (slowest-of-16-waves arrival, twice) + an LDS hop every
//    step; r5/r8-r11 falsified all instruction-level terms; this removes the
//    block-coupling structurally. Only sync left = the ring tags (data dep).
//  - Intra-layer skew is self-bounded <=1 step (step t needs ALL layer posts
//    of t-1), so RING=64 slots can't overwrite unread intra-layer data.
//    Cross-layer: every-8-steps prog backpressure (margin 40+8 < 64).
//  - All cross-CU ops: __hip_atomic_* agent scope / sc1 asm (proven path).
// ---------------------------------------------------------------------------

#define T_SEQ 4096
#define HDIM  512
#define NL    16
#define BPL   16
#define NTH   1024
#define RING  64
#define RW    256     // u64 words per layer-slot (2 f16 h each)

typedef unsigned long long u64;
typedef _Float16 half2v __attribute__((ext_vector_type(2)));

struct Args {
  const float* x;
  const float* Wih[NL]; const float* Whh[NL];
  const float* bih[NL]; const float* bhh[NL];
  u64* ring;        // [NL][RING][RW] {tag32 | 2xf16}
  unsigned* prog;   // [(NL+1)*BPL]
  float* sout;      // [T_SEQ][HDIM]
};

__device__ __forceinline__ void astoreU(u64* p, u64 v) {
  __hip_atomic_store(p, v, __ATOMIC_RELAXED, __HIP_MEMORY_SCOPE_AGENT);
}
__device__ __forceinline__ unsigned aloadu(const unsigned* p) {
  return __hip_atomic_load(p, __ATOMIC_RELAXED, __HIP_MEMORY_SCOPE_AGENT);
}
__device__ __forceinline__ void astoreu(unsigned* p, unsigned v) {
  __hip_atomic_store(p, v, __ATOMIC_RELAXED, __HIP_MEMORY_SCOPE_AGENT);
}
__device__ __forceinline__ float sigm(float x) { return 1.f / (1.f + __expf(-x)); }
__device__ __forceinline__ float tanhx(float x) {
  const float e = __expf(-2.f * fabsf(x));
  return copysignf((1.f - e) / (1.f + e), x);
}

// 16B sc1 load, issue/wait split (r11-proven pattern). sched_barrier stops
// hipcc hoisting the register-only tag checks above the wait (rule #18).
#define LD16(r, p) \
  asm volatile("global_load_dwordx4 %0, %1, off sc1" : "=v"(r) : "v"(p))
#define WAITV()                                          \
  do {                                                   \
    asm volatile("s_waitcnt vmcnt(0)" ::: "memory");     \
    __builtin_amdgcn_sched_barrier(0);                   \
  } while (0)

#if __has_builtin(__builtin_amdgcn_fdot2)
#define DOT2(w, v, acc) __builtin_amdgcn_fdot2((w), (v), (acc), false)
#else
__device__ __forceinline__ float DOT2(half2v w, half2v v, float acc) {
  return acc + (float)w.x * (float)v.x + (float)w.y * (float)v.y;
}
#endif

#define BC(u) __builtin_bit_cast(half2v, (u))
// acc += W[0..3] . {q0..q3}
#define DO4(acc, W, q0, q1, q2, q3)                      \
  acc = DOT2(W[0], q0, acc); acc = DOT2(W[1], q1, acc);  \
  acc = DOT2(W[2], q2, acc); acc = DOT2(W[3], q3, acc)

__global__ void __launch_bounds__(NTH) lstm16_kernel(Args a)
{
  const int tid   = threadIdx.x;
  const int layer = blockIdx.x & 15;
  const int b     = blockIdx.x >> 4;
  const int wv    = tid >> 6;          // 0..15: wave = engine for 2 h
  const int cs    = tid & 63;          // 0..63: 8-float k-slice
  const int kx    = cs * 8;
  const int hi0   = b * 32 + 2 * wv;
  const int D     = layer ? HDIM : 128;
  const bool xok  = (kx + 8 <= D);

  // ---- weights: [hi][gate][4 half2] x {x,h} = 64 u32 ----
  half2v wx[2][4][4], wh[2][4][4];
  float  bs[2][4];
  #pragma unroll
  for (int j = 0; j < 2; ++j) {
    #pragma unroll
    for (int q = 0; q < 4; ++q) {
      const int row = q * HDIM + hi0 + j;
      bs[j][q] = a.bih[layer][row] + a.bhh[layer][row];
      const float2* px = (const float2*)(a.Wih[layer] + (size_t)row * D + kx);
      const float2* ph = (const float2*)(a.Whh[layer] + (size_t)row * HDIM + kx);
      #pragma unroll
      for (int m = 0; m < 4; ++m) {
        const float2 t0 = xok ? px[m] : make_float2(0.f, 0.f);
        const float2 t1 = ph[m];
        half2v w0; w0.x = (_Float16)t0.x; w0.y = (_Float16)t0.y; wx[j][q][m] = w0;
        half2v w1; w1.x = (_Float16)t1.x; w1.y = (_Float16)t1.y; wh[j][q][m] = w1;
      }
    }
  }

  u64* rOwn        = a.ring + (size_t)layer * RING * RW;
  const u64* rPrev = a.ring + (size_t)(layer ? layer - 1 : 0) * RING * RW;
  const unsigned* progNext = a.prog + (layer + 1) * BPL;
  unsigned* myprog         = a.prog + layer * BPL + b;

  float c_state = 0.f;   // live on lanes 0,1 (one per h-index)

  for (int t = 0; t < T_SEQ; ++t) {
    const int slot = t & (RING - 1);
    const unsigned xtag = (unsigned)(t + 1);

    // ---- x(t): direct tagged load (layer>0) or global fp32 (layer 0) ----
    half2v xp0, xp1, xp2, xp3;
    if (layer == 0) {
      if (xok) {
        const float4* xs = (const float4*)(a.x + (size_t)t * 128 + kx);
        const float4 f0 = xs[0], f1 = xs[1];
        xp0.x = (_Float16)f0.x; xp0.y = (_Float16)f0.y;
        xp1.x = (_Float16)f0.z; xp1.y = (_Float16)f0.w;
        xp2.x = (_Float16)f1.x; xp2.y = (_Float16)f1.y;
        xp3.x = (_Float16)f1.z; xp3.y = (_Float16)f1.w;
      } else {
        xp0 = BC(0u); xp1 = BC(0u); xp2 = BC(0u); xp3 = BC(0u);
      }
    } else {
      const uint4* px = (const uint4*)(rPrev + (size_t)slot * RW) + cs * 2;
      uint4 xa, xb;
      LD16(xa, px); LD16(xb, px + 1); WAITV();
      bool ok = (xa.y == xtag) & (xa.w == xtag) &
                (xb.y == xtag) & (xb.w == xtag);
      while (!__all(ok)) {
        if (!ok) {
          __builtin_amdgcn_s_sleep(1);
          LD16(xa, px); LD16(xb, px + 1); WAITV();
          ok = (xa.y == xtag) & (xa.w == xtag) &
               (xb.y == xtag) & (xb.w == xtag);
        }
      }
      xp0 = BC(xa.x); xp1 = BC(xa.z); xp2 = BC(xb.x); xp3 = BC(xb.z);
    }

    float a00 = 0.f, a01 = 0.f, a02 = 0.f, a03 = 0.f;
    float a10 = 0.f, a11 = 0.f, a12 = 0.f, a13 = 0.f;
    DO4(a00, wx[0][0], xp0, xp1, xp2, xp3);
    DO4(a01, wx[0][1], xp0, xp1, xp2, xp3);
    DO4(a02, wx[0][2], xp0, xp1, xp2, xp3);
    DO4(a03, wx[0][3], xp0, xp1, xp2, xp3);
    DO4(a10, wx[1][0], xp0, xp1, xp2, xp3);
    DO4(a11, wx[1][1], xp0, xp1, xp2, xp3);
    DO4(a12, wx[1][2], xp0, xp1, xp2, xp3);
    DO4(a13, wx[1][3], xp0, xp1, xp2, xp3);

    // ---- h(t-1): direct tagged load, spin, dots ----
    if (t > 0) {
      const uint4* ph =
          (const uint4*)(rOwn + (size_t)((t - 1) & (RING - 1)) * RW) + cs * 2;
      uint4 ha, hb;
      LD16(ha, ph); LD16(hb, ph + 1); WAITV();
      const unsigned htag = (unsigned)t;
      bool ok = (ha.y == htag) & (ha.w == htag) &
                (hb.y == htag) & (hb.w == htag);
      while (!__all(ok)) {
        if (!ok) {
          __builtin_amdgcn_s_sleep(1);
          LD16(ha, ph); LD16(hb, ph + 1); WAITV();
          ok = (ha.y == htag) & (ha.w == htag) &
               (hb.y == htag) & (hb.w == htag);
        }
      }
      const half2v hp0 = BC(ha.x), hp1 = BC(ha.z);
      const half2v hp2 = BC(hb.x), hp3 = BC(hb.z);
      DO4(a00, wh[0][0], hp0, hp1, hp2, hp3);
      DO4(a01, wh[0][1], hp0, hp1, hp2, hp3);
      DO4(a02, wh[0][2], hp0, hp1, hp2, hp3);
      DO4(a03, wh[0][3], hp0, hp1, hp2, hp3);
      DO4(a10, wh[1][0], hp0, hp1, hp2, hp3);
      DO4(a11, wh[1][1], hp0, hp1, hp2, hp3);
      DO4(a12, wh[1][2], hp0, hp1, hp2, hp3);
      DO4(a13, wh[1][3], hp0, hp1, hp2, hp3);
    }

    // ---- 64-lane butterfly reduce (intra-wave, no barrier) ----
    #pragma unroll
    for (int d = 1; d < 64; d <<= 1) {
      a00 += __shfl_xor(a00, d); a01 += __shfl_xor(a01, d);
      a02 += __shfl_xor(a02, d); a03 += __shfl_xor(a03, d);
      a10 += __shfl_xor(a10, d); a11 += __shfl_xor(a11, d);
      a12 += __shfl_xor(a12, d); a13 += __shfl_xor(a13, d);
    }

    // ---- gates on lanes 0 (hi0) and 1 (hi0+1) ----
    float hval = 0.f;
    if (cs < 2) {
      const float vi = cs ? a10 : a00;
      const float vf = cs ? a11 : a01;
      const float vg = cs ? a12 : a02;
      const float vo = cs ? a13 : a03;
      const float b0 = cs ? bs[1][0] : bs[0][0];
      const float b1 = cs ? bs[1][1] : bs[0][1];
      const float b2 = cs ? bs[1][2] : bs[0][2];
      const float b3 = cs ? bs[1][3] : bs[0][3];
      const float gi = sigm(vi + b0);
      const float gf = sigm(vf + b1);
      const float gg = tanhx(vg + b2);
      const float go = sigm(vo + b3);
      c_state = gf * c_state + gi * gg;
      hval = go * tanhx(c_state);
    }
    const float hodd = __shfl(hval, 1);   // lane1's h, read on lane0
    if (cs == 0) {
      half2v pk; pk.x = (_Float16)hval; pk.y = (_Float16)hodd;
      astoreU(rOwn + (size_t)slot * RW + (b * 16 + wv),
              ((u64)xtag << 32) | (u64)__builtin_bit_cast(unsigned, pk));
    }
    if (layer == NL - 1 && cs < 2)
      a.sout[(size_t)t * HDIM + hi0 + cs] = hval;

    // ---- progress + backpressure (every 8 steps, off critical path) ----
    if ((t & 7) == 7) {
      if (tid == 0) astoreu(myprog, (unsigned)(t + 1));
      if (layer < NL - 1) {
        bool bok = (cs >= BPL) || ((int)aloadu(progNext + cs) >= t - 40);
        while (!__all(bok)) {
          if (!bok) {
            __builtin_amdgcn_s_sleep(2);
            bok = ((int)aloadu(progNext + cs) >= t - 40);
          }
        }
      }
    }
  }
}

// ---------------- MLP head: (T,512) -> 64 -> 32 -> 16 ----------------
__global__ void __launch_bounds__(64) mlp_head_kernel(
    const float* __restrict__ S,
    const float* __restrict__ w1, const float* __restrict__ b1,
    const float* __restrict__ w2, const float* __restrict__ b2,
    const float* __restrict__ w3, const float* __restrict__ b3,
    float* __restrict__ out)
{
  const int r   = blockIdx.x;
  const int tid = threadIdx.x;
  __shared__ __align__(16) float hbuf[HDIM];
  __shared__ float a1[64];
  __shared__ float a2[32];

  #pragma unroll
  for (int u = 0; u < HDIM / 64; ++u)
    hbuf[u * 64 + tid] = S[(size_t)r * HDIM + u * 64 + tid];
  __syncthreads();

  float acc = b1[tid];
  {
    const float4* w4 = (const float4*)(w1 + (size_t)tid * HDIM);
    const float4* h4 = (const float4*)hbuf;
    #pragma unroll 8
    for (int k = 0; k < HDIM / 4; ++k) {
      const float4 wv = w4[k], hv = h4[k];
      acc = fmaf(wv.x, hv.x, acc); acc = fmaf(wv.y, hv.y, acc);
      acc = fmaf(wv.z, hv.z, acc); acc = fmaf(wv.w, hv.w, acc);
    }
  }
  a1[tid] = acc * sigm(acc);
  __syncthreads();

  if (tid < 32) {
    float acc2 = b2[tid];
    #pragma unroll
    for (int k = 0; k < 64; ++k) acc2 = fmaf(a1[k], w2[tid * 64 + k], acc2);
    a2[tid] = acc2 * sigm(acc2);
  }
  __syncthreads();

  if (tid < 16) {
    float acc3 = b3[tid];
    #pragma unroll
    for (int k = 0; k < 32; ++k) acc3 = fmaf(a2[k], w3[tid * 32 + k], acc3);
    out[(size_t)r * 16 + tid] = acc3;
  }
}

// ---------------------------------------------------------------------------
extern "C" void kernel_launch(void* const* d_in, const int* in_sizes, int n_in,
                              void* d_out, int out_size, void* d_ws, size_t ws_size,
                              hipStream_t stream)
{
  (void)in_sizes; (void)n_in; (void)out_size; (void)ws_size;

  const float* x     = (const float*)d_in[0];
  const float* eWih0 = (const float*)d_in[1];
  const float* eWhh0 = (const float*)d_in[2];
  const float* ebih0 = (const float*)d_in[3];
  const float* ebhh0 = (const float*)d_in[4];
  const float* eWih  = (const float*)d_in[5];
  const float* eWhh  = (const float*)d_in[6];
  const float* ebih  = (const float*)d_in[7];
  const float* ebhh  = (const float*)d_in[8];
  const float* dWih  = (const float*)d_in[9];
  const float* dWhh  = (const float*)d_in[10];
  const float* dbih  = (const float*)d_in[11];
  const float* dbhh  = (const float*)d_in[12];
  const float* fc1w  = (const float*)d_in[13];
  const float* fc1b  = (const float*)d_in[14];
  const float* fc2w  = (const float*)d_in[15];
  const float* fc2b  = (const float*)d_in[16];
  const float* fc3w  = (const float*)d_in[17];
  const float* fc3b  = (const float*)d_in[18];
  float* out = (float*)d_out;

  // ws layout: ring 2 MB | prog 4 KB | sout 8 MB
  const size_t RINGBYTES = (size_t)NL * RING * RW * sizeof(u64);  // 2 MB
  Args p{};
  p.x    = x;
  p.ring = (u64*)d_ws;
  p.prog = (unsigned*)((char*)d_ws + RINGBYTES);
  p.sout = (float*)((char*)d_ws + RINGBYTES + 4096);

  p.Wih[0] = eWih0; p.Whh[0] = eWhh0; p.bih[0] = ebih0; p.bhh[0] = ebhh0;
  for (int l = 1; l < 8; ++l) {
    p.Wih[l] = eWih + (size_t)(l - 1) * 4 * HDIM * HDIM;
    p.Whh[l] = eWhh + (size_t)(l - 1) * 4 * HDIM * HDIM;
    p.bih[l] = ebih + (size_t)(l - 1) * 4 * HDIM;
    p.bhh[l] = ebhh + (size_t)(l - 1) * 4 * HDIM;
  }
  for (int l = 8; l < 16; ++l) {
    p.Wih[l] = dWih + (size_t)(l - 8) * 4 * HDIM * HDIM;
    p.Whh[l] = dWhh + (size_t)(l - 8) * 4 * HDIM * HDIM;
    p.bih[l] = dbih + (size_t)(l - 8) * 4 * HDIM;
    p.bhh[l] = dbhh + (size_t)(l - 8) * 4 * HDIM;
  }

  // clear ring tags + prog each launch -> replay-safe
  (void)hipMemsetAsync(d_ws, 0, RINGBYTES + 4096, stream);

  void* args[] = { &p };
  hipError_t e = hipLaunchCooperativeKernel((const void*)lstm16_kernel,
                                            dim3(NL * BPL), dim3(NTH), args, 0,
                                            stream);
  if (e != hipSuccess)   // 256 blocks @ 1/CU on 256 CUs: co-resident anyway
    lstm16_kernel<<<dim3(NL * BPL), dim3(NTH), 0, stream>>>(p);

  mlp_head_kernel<<<dim3(T_SEQ), dim3(64), 0, stream>>>(
      p.sout, fc1w, fc1b, fc2w, fc2b, fc3w, fc3b, out);
}

// Round 13
// 9188.419 us; speedup vs baseline: 4.7071x; 4.7071x over previous
//
#include <hip/hip_runtime.h>
#include <math.h>

// ---------------------------------------------------------------------------
// Fused 16-layer LSTM pipeline (H=512, T=4096) + MLP head.
// EXACT round-4 structure (best verified: 9.24 ms) with ONE change:
//   ring posts go out as global_atomic_swap (fire-and-forget, result unused,
//   no sc0) instead of plain sc1 stores. Theory: a relaxed global store
//   drains through write-coalescing buffers before it reaches the MALL;
//   the consumers' polls (r8-r12 falsified every consumer-side term) spin
//   on that hidden producer-side visibility latency. An atomic RMW is
//   executed AT the memory endpoint -> injected into the fabric directly,
//   visible ~one RT sooner. Same value/slot -> replay-deterministic.
//
//  - 256 blocks = 16 layers x 16 blocks/layer, 1024 thr (16 waves), 1/CU.
//  - Per thread: 1 h-index x 4 gates x 16-k slice, weights f16-packed in
//    64 u32 (reg-resident; FETCH evidence shows no memory spill).
//  - Ring atoms {tag32 | f32 h} u64, relaxed agent-scope loads; posts atomic.
//  - Waves 0-7 poll h; waves 8-15 stage x one step ahead (parity dbuf).
//  - Posts PRE-BAR2 (r5: load-bearing). LDS dedup + specialized pollers
//    (r12 proved direct per-wave polling collapses the fabric).
// ---------------------------------------------------------------------------

#define T_SEQ 4096
#define HDIM  512
#define NL    16
#define BPL   16
#define NTH   1024
#define RING  64

typedef unsigned long long u64;
typedef _Float16 half2v __attribute__((ext_vector_type(2)));

struct Args {
  const float* x;
  const float* Wih[NL]; const float* Whh[NL];
  const float* bih[NL]; const float* bhh[NL];
  u64* ring;        // [NL][RING][HDIM] tagged h
  unsigned* prog;   // [(NL+1)*BPL] progress flags
  float* sout;      // [T_SEQ][HDIM]
};

__device__ __forceinline__ u64 aloadU(const u64* p) {
  return __hip_atomic_load(p, __ATOMIC_RELAXED, __HIP_MEMORY_SCOPE_AGENT);
}
// fire-and-forget endpoint post: atomic swap, result discarded (no sc0)
__device__ __forceinline__ void apostU(u64* p, u64 v) {
  (void)__hip_atomic_exchange(p, v, __ATOMIC_RELAXED, __HIP_MEMORY_SCOPE_AGENT);
}
__device__ __forceinline__ unsigned aloadu(const unsigned* p) {
  return __hip_atomic_load(p, __ATOMIC_RELAXED, __HIP_MEMORY_SCOPE_AGENT);
}
__device__ __forceinline__ float sigm(float x) { return 1.f / (1.f + __expf(-x)); }
__device__ __forceinline__ float tanhx(float x) {
  const float e = __expf(-2.f * fabsf(x));
  return copysignf((1.f - e) / (1.f + e), x);
}

#if __has_builtin(__builtin_amdgcn_fdot2)
#define DOT2(w, v, acc) __builtin_amdgcn_fdot2((w), (v), (acc), false)
#else
__device__ __forceinline__ float DOT2(half2v w, half2v v, float acc) {
  return acc + (float)w.x * (float)v.x + (float)w.y * (float)v.y;
}
#endif

#define BC(u) __builtin_bit_cast(half2v, (u))
#define DOTS8(acc, W) \
  acc = DOT2(W[0], p0, acc); acc = DOT2(W[1], p1, acc); \
  acc = DOT2(W[2], p2, acc); acc = DOT2(W[3], p3, acc); \
  acc = DOT2(W[4], p4, acc); acc = DOT2(W[5], p5, acc); \
  acc = DOT2(W[6], p6, acc); acc = DOT2(W[7], p7, acc)

__global__ void __launch_bounds__(NTH) lstm16_kernel(Args a)
{
  const int tid   = threadIdx.x;
  const int layer = blockIdx.x & 15;
  const int b     = blockIdx.x >> 4;
  const int hi    = tid >> 5;          // 0..31: h-index within block
  const int cs    = tid & 31;          // 0..31: k-chunk (16x + 16h floats)
  const int kx    = cs * 16;
  const int hq    = b * 32 + hi;
  const int D     = layer ? HDIM : 128;

  // ---- weights: all 4 gates f16-packed, 64 VGPRs total ----
  half2v wx[4][8], wh[4][8];
  float  bs[4];
  const bool xok = (kx + 16 <= D);
  #pragma unroll
  for (int q = 0; q < 4; ++q) {
    const int row = q * HDIM + hq;
    bs[q] = a.bih[layer][row] + a.bhh[layer][row];
    const float2* px = (const float2*)(a.Wih[layer] + (size_t)row * D + kx);
    const float2* ph = (const float2*)(a.Whh[layer] + (size_t)row * HDIM + kx);
    #pragma unroll
    for (int p = 0; p < 8; ++p) {
      const float2 t0 = xok ? px[p] : make_float2(0.f, 0.f);
      const float2 t1 = ph[p];
      half2v w0; w0.x = (_Float16)t0.x; w0.y = (_Float16)t0.y; wx[q][p] = w0;
      half2v w1; w1.x = (_Float16)t1.x; w1.y = (_Float16)t1.y; wh[q][p] = w1;
    }
  }

  // LDS: x parity-double-buffered, h single (stride 10 u32 -> 2-way = free)
  __shared__ __align__(8) unsigned vx16[2][320];
  __shared__ __align__(8) unsigned vh16[320];

  u64* ringOwn        = a.ring + (size_t)layer * RING * HDIM;
  const u64* ringPrev = a.ring + (size_t)(layer ? layer - 1 : 0) * RING * HDIM;
  const unsigned* progNext = a.prog + (layer + 1) * BPL;
  unsigned* myprog         = a.prog + layer * BPL + b;

  // ---- x staging for step tt into vx16[tt&1] (waves 8-15 only) ----
  auto stage_x = [&](int tt) {
    if (tid < 512) return;
    const int w = tid - 512;
    bool okbp = !((layer < NL - 1) && (w < 16) && ((tt & 7) == 0));
    float xv = 0.f;
    if (layer == 0) {
      if (w < 128) xv = a.x[(size_t)tt * 128 + w];
      if (!okbp)
        while ((int)aloadu(progNext + w) < tt - 40) __builtin_amdgcn_s_sleep(2);
    } else {
      const u64* xw = ringPrev + (size_t)(tt & (RING - 1)) * HDIM + w;
      u64 u = aloadU(xw);
      bool ok = ((unsigned)(u >> 32) == (unsigned)(tt + 1));
      while (!__all(ok & okbp)) {
        if (!ok) {
          u = aloadU(xw);
          ok = ((unsigned)(u >> 32) == (unsigned)(tt + 1));
          if (!ok) __builtin_amdgcn_s_sleep(1);
        }
        if (!okbp) okbp = ((int)aloadu(progNext + w) >= tt - 40);
      }
      xv = __builtin_bit_cast(float, (unsigned)(u & 0xffffffffu));
    }
    const float nb = __shfl_down(xv, 1);
    if (!(w & 1)) {
      half2v pk; pk.x = (_Float16)xv; pk.y = (_Float16)nb;
      vx16[tt & 1][(w >> 4) * 10 + ((w & 15) >> 1)] =
          __builtin_bit_cast(unsigned, pk);
    }
  };

  stage_x(0);
  __syncthreads();

  float c_state = 0.f;   // lanes cs==0 own h-index hq

  for (int t = 0; t < T_SEQ; ++t) {
    // ---- issue h tagged-load early (waves 0-7; hides under x-dots) ----
    u64 hu = 0; const u64* hw = ringOwn;
    const bool hpoll = (t > 0) && (tid < 512);
    if (hpoll) {
      hw = ringOwn + (size_t)((t - 1) & (RING - 1)) * HDIM + tid;
      hu = aloadU(hw);
    }

    // ---- x-dots from vx16[t&1] (staged last iteration) ----
    float a0 = 0.f, a1 = 0.f, a2 = 0.f, a3 = 0.f;
    {
      const unsigned* vb = vx16[t & 1] + cs * 10;
      const uint2 u0 = *(const uint2*)(vb + 0);
      const uint2 u1 = *(const uint2*)(vb + 2);
      const uint2 u2 = *(const uint2*)(vb + 4);
      const uint2 u3 = *(const uint2*)(vb + 6);
      const half2v p0 = BC(u0.x), p1 = BC(u0.y), p2 = BC(u1.x), p3 = BC(u1.y);
      const half2v p4 = BC(u2.x), p5 = BC(u2.y), p6 = BC(u3.x), p7 = BC(u3.y);
      DOTS8(a0, wx[0]); DOTS8(a1, wx[1]); DOTS8(a2, wx[2]); DOTS8(a3, wx[3]);
    }

    // ---- h: finish poll, stage, dots ----
    if (t > 0) {
      if (tid < 512) {
        bool ok = ((unsigned)(hu >> 32) == (unsigned)t);
        while (!__all(ok)) {
          if (!ok) { hu = aloadU(hw); ok = ((unsigned)(hu >> 32) == (unsigned)t); }
        }
        const float hv = __builtin_bit_cast(float, (unsigned)(hu & 0xffffffffu));
        const float nb = __shfl_down(hv, 1);
        if (!(tid & 1)) {
          half2v pk; pk.x = (_Float16)hv; pk.y = (_Float16)nb;
          vh16[(tid >> 4) * 10 + ((tid & 15) >> 1)] =
              __builtin_bit_cast(unsigned, pk);
        }
      }
      __syncthreads();   // BAR1: vh staged
      {
        const unsigned* vb = vh16 + cs * 10;
        const uint2 u0 = *(const uint2*)(vb + 0);
        const uint2 u1 = *(const uint2*)(vb + 2);
        const uint2 u2 = *(const uint2*)(vb + 4);
        const uint2 u3 = *(const uint2*)(vb + 6);
        const half2v p0 = BC(u0.x), p1 = BC(u0.y), p2 = BC(u1.x), p3 = BC(u1.y);
        const half2v p4 = BC(u2.x), p5 = BC(u2.y), p6 = BC(u3.x), p7 = BC(u3.y);
        DOTS8(a0, wh[0]); DOTS8(a1, wh[1]); DOTS8(a2, wh[2]); DOTS8(a3, wh[3]);
      }
    }

    // ---- reduce across 32 k-lanes (stays within 32-lane halves) ----
    #pragma unroll
    for (int d = 1; d < 32; d <<= 1) {
      a0 += __shfl_xor(a0, d); a1 += __shfl_xor(a1, d);
      a2 += __shfl_xor(a2, d); a3 += __shfl_xor(a3, d);
    }

    // ---- gates + ATOMIC post (lanes cs==0: one per h-index; pre-BAR2) ----
    if (cs == 0) {
      const float gi = sigm(a0 + bs[0]);
      const float gf = sigm(a1 + bs[1]);
      const float gg = tanhx(a2 + bs[2]);
      const float go = sigm(a3 + bs[3]);
      c_state = gf * c_state + gi * gg;
      const float h = go * tanhx(c_state);
      apostU(ringOwn + (size_t)(t & (RING - 1)) * HDIM + hq,
             ((u64)(unsigned)(t + 1) << 32) | (u64)__builtin_bit_cast(unsigned, h));
      if (layer == NL - 1) a.sout[(size_t)t * HDIM + hq] = h;
    }
    if (tid == 0 && (t & 7) == 7)
      __hip_atomic_store(myprog, (unsigned)(t + 1), __ATOMIC_RELAXED,
                         __HIP_MEMORY_SCOPE_AGENT);

    // ---- prefetch x_{t+1} (slack path, waves 8-15) ----
    if (t + 1 < T_SEQ) stage_x(t + 1);
    __syncthreads();     // BAR2
  }
}

// ---------------- MLP head: (T,512) -> 64 -> 32 -> 16 ----------------
__global__ void __launch_bounds__(64) mlp_head_kernel(
    const float* __restrict__ S,
    const float* __restrict__ w1, const float* __restrict__ b1,
    const float* __restrict__ w2, const float* __restrict__ b2,
    const float* __restrict__ w3, const float* __restrict__ b3,
    float* __restrict__ out)
{
  const int r   = blockIdx.x;
  const int tid = threadIdx.x;
  __shared__ __align__(16) float hbuf[HDIM];
  __shared__ float a1[64];
  __shared__ float a2[32];

  #pragma unroll
  for (int u = 0; u < HDIM / 64; ++u)
    hbuf[u * 64 + tid] = S[(size_t)r * HDIM + u * 64 + tid];
  __syncthreads();

  float acc = b1[tid];
  {
    const float4* w4 = (const float4*)(w1 + (size_t)tid * HDIM);
    const float4* h4 = (const float4*)hbuf;
    #pragma unroll 8
    for (int k = 0; k < HDIM / 4; ++k) {
      const float4 wv = w4[k], hv = h4[k];
      acc = fmaf(wv.x, hv.x, acc); acc = fmaf(wv.y, hv.y, acc);
      acc = fmaf(wv.z, hv.z, acc); acc = fmaf(wv.w, hv.w, acc);
    }
  }
  a1[tid] = acc * sigm(acc);
  __syncthreads();

  if (tid < 32) {
    float acc2 = b2[tid];
    #pragma unroll
    for (int k = 0; k < 64; ++k) acc2 = fmaf(a1[k], w2[tid * 64 + k], acc2);
    a2[tid] = acc2 * sigm(acc2);
  }
  __syncthreads();

  if (tid < 16) {
    float acc3 = b3[tid];
    #pragma unroll
    for (int k = 0; k < 32; ++k) acc3 = fmaf(a2[k], w3[tid * 32 + k], acc3);
    out[(size_t)r * 16 + tid] = acc3;
  }
}

// ---------------------------------------------------------------------------
extern "C" void kernel_launch(void* const* d_in, const int* in_sizes, int n_in,
                              void* d_out, int out_size, void* d_ws, size_t ws_size,
                              hipStream_t stream)
{
  (void)in_sizes; (void)n_in; (void)out_size; (void)ws_size;

  const float* x     = (const float*)d_in[0];
  const float* eWih0 = (const float*)d_in[1];
  const float* eWhh0 = (const float*)d_in[2];
  const float* ebih0 = (const float*)d_in[3];
  const float* ebhh0 = (const float*)d_in[4];
  const float* eWih  = (const float*)d_in[5];
  const float* eWhh  = (const float*)d_in[6];
  const float* ebih  = (const float*)d_in[7];
  const float* ebhh  = (const float*)d_in[8];
  const float* dWih  = (const float*)d_in[9];
  const float* dWhh  = (const float*)d_in[10];
  const float* dbih  = (const float*)d_in[11];
  const float* dbhh  = (const float*)d_in[12];
  const float* fc1w  = (const float*)d_in[13];
  const float* fc1b  = (const float*)d_in[14];
  const float* fc2w  = (const float*)d_in[15];
  const float* fc2b  = (const float*)d_in[16];
  const float* fc3w  = (const float*)d_in[17];
  const float* fc3b  = (const float*)d_in[18];
  float* out = (float*)d_out;

  // ws layout: ring 4 MB | prog (4 KB) | sout 8 MB
  const size_t RINGBYTES = (size_t)NL * RING * HDIM * sizeof(u64);  // 4 MB
  Args p{};
  p.x    = x;
  p.ring = (u64*)d_ws;
  p.prog = (unsigned*)((char*)d_ws + RINGBYTES);
  p.sout = (float*)((char*)d_ws + RINGBYTES + 4096);

  p.Wih[0] = eWih0; p.Whh[0] = eWhh0; p.bih[0] = ebih0; p.bhh[0] = ebhh0;
  for (int l = 1; l < 8; ++l) {
    p.Wih[l] = eWih + (size_t)(l - 1) * 4 * HDIM * HDIM;
    p.Whh[l] = eWhh + (size_t)(l - 1) * 4 * HDIM * HDIM;
    p.bih[l] = ebih + (size_t)(l - 1) * 4 * HDIM;
    p.bhh[l] = ebhh + (size_t)(l - 1) * 4 * HDIM;
  }
  for (int l = 8; l < 16; ++l) {
    p.Wih[l] = dWih + (size_t)(l - 8) * 4 * HDIM * HDIM;
    p.Whh[l] = dWhh + (size_t)(l - 8) * 4 * HDIM * HDIM;
    p.bih[l] = dbih + (size_t)(l - 8) * 4 * HDIM;
    p.bhh[l] = dbhh + (size_t)(l - 8) * 4 * HDIM;
  }

  // clear rings (tags) + progress flags each launch -> replay-safe
  (void)hipMemsetAsync(d_ws, 0, RINGBYTES + 4096, stream);

  void* args[] = { &p };
  hipError_t e = hipLaunchCooperativeKernel((const void*)lstm16_kernel,
                                            dim3(NL * BPL), dim3(NTH), args, 0,
                                            stream);
  if (e != hipSuccess)   // 256 blocks @ 1/CU on 256 CUs: co-resident anyway
    lstm16_kernel<<<dim3(NL * BPL), dim3(NTH), 0, stream>>>(p);

  mlp_head_kernel<<<dim3(T_SEQ), dim3(64), 0, stream>>>(
      p.sout, fc1w, fc1b, fc2w, fc2b, fc3w, fc3b, out);
}